// Round 20
// baseline (103.860 us; speedup 1.0000x reference)
//
#include <hip/hip_runtime.h>

// B=4, C=512, L=2048, H=8, Ch=64, BH=32
// prep: w->bf16 wcat[1536][512]; x->xT[b][l][c] bf16
// proj: MFMA 32x32x16, 128x128 tile. r20: BK=32 double-buffer (LDS 32KB loop /
//       33.3KB epi -> 4 blocks/CU, was 2 at BK=64) + r19 vector epilogue.
// vtrans: vv -> vtg (b,h,c,m) bf16  (V^T of the .view-reshaped v2)
// attn: r15-proven flash loop (LDS dbuf, two barriers, pre-barrier STAGE,
//       no-max softmax, VALU l-sum, XCD swizzle, setprio, bf16 partials).
// combine: out = (b2f(p0) + b2f(p1)) / (l0 + l1)

typedef unsigned short u16;
typedef unsigned int   u32;
typedef short bf16x8 __attribute__((ext_vector_type(8)));
typedef u16  u16x8  __attribute__((ext_vector_type(8)));
typedef float f32x16 __attribute__((ext_vector_type(16)));

#define SCALE_Q 0.18033688011112042f  // 0.125 * log2(e)

__device__ __forceinline__ u16 f2b(float f) {
    u32 u = __float_as_uint(f);
    u += 0x7FFFu + ((u >> 16) & 1u);
    return (u16)(u >> 16);
}

__device__ __forceinline__ float b2f(u16 v) {
    u32 u = ((u32)v) << 16;
    return __uint_as_float(u);
}

__device__ __forceinline__ float exp2_(float x) {
#if __has_builtin(__builtin_amdgcn_exp2f)
    return __builtin_amdgcn_exp2f(x);
#else
    return exp2f(x);
#endif
}

__device__ __forceinline__ u32 cvtpk(float lo, float hi) {
    u32 d;
    asm("v_cvt_pk_bf16_f32 %0, %1, %2" : "=v"(d) : "v"(lo), "v"(hi));
    return d;
}

__device__ __forceinline__ void pl32swap(u32& a, u32& b) {
    asm volatile("v_permlane32_swap_b32 %0, %1" : "+v"(a), "+v"(b));
}

__device__ __forceinline__ void g2l16(const u16* g, u16* l) {
    __builtin_amdgcn_global_load_lds(
        (const __attribute__((address_space(1))) unsigned int*)g,
        (__attribute__((address_space(3))) unsigned int*)l, 16, 0, 0);
}

#define WAITV(N) asm volatile("s_waitcnt vmcnt(" #N ")" ::: "memory")
#define WAITL0   asm volatile("s_waitcnt lgkmcnt(0)" ::: "memory")
#define SBAR     __builtin_amdgcn_s_barrier()
#define SCHED0   __builtin_amdgcn_sched_barrier(0)

// ---------------- prep: convert W, transpose+convert X ----------------
__global__ __launch_bounds__(256) void prep_kernel(
    const float* __restrict__ wq, const float* __restrict__ wk,
    const float* __restrict__ wv, const float* __restrict__ x,
    u16* __restrict__ wcat, u16* __restrict__ xT)
{
    const int bid = blockIdx.x, t = threadIdx.x;
    if (bid < 384) {
        int e0 = bid * 2048 + t * 8;
        const float* src = (e0 < 262144) ? wq : (e0 < 524288) ? wk : wv;
        int eo = e0 & 262143;
        float4 a = *(const float4*)(src + eo);
        float4 b = *(const float4*)(src + eo + 4);
        u16x8 o;
        o[0]=f2b(a.x); o[1]=f2b(a.y); o[2]=f2b(a.z); o[3]=f2b(a.w);
        o[4]=f2b(b.x); o[5]=f2b(b.y); o[6]=f2b(b.z); o[7]=f2b(b.w);
        *(u16x8*)(wcat + e0) = o;
        return;
    }
    int xb = bid - 384;
    int b = xb >> 8, ct = (xb >> 5) & 7, lt = xb & 31;
    __shared__ float lds[64 * 65];
#pragma unroll
    for (int it = 0; it < 4; ++it) {
        int s = t + it * 256;
        int cr = s >> 4, l4 = (s & 15) * 4;
        float4 v = *(const float4*)(x + ((size_t)(b * 512 + ct * 64 + cr)) * 2048 + lt * 64 + l4);
        lds[(l4 + 0) * 65 + cr] = v.x;
        lds[(l4 + 1) * 65 + cr] = v.y;
        lds[(l4 + 2) * 65 + cr] = v.z;
        lds[(l4 + 3) * 65 + cr] = v.w;
    }
    __syncthreads();
    {
        int l = t >> 2, c16 = (t & 3) * 16;
        u16x8 o0, o1;
#pragma unroll
        for (int i = 0; i < 8; ++i) o0[i] = f2b(lds[l * 65 + c16 + i]);
#pragma unroll
        for (int i = 0; i < 8; ++i) o1[i] = f2b(lds[l * 65 + c16 + 8 + i]);
        u16* d = xT + ((size_t)(b * 2048 + lt * 64 + l)) * 512 + ct * 64 + c16;
        *(u16x8*)d = o0;
        *(u16x8*)(d + 8) = o1;
    }
}

// ---------------- proj: fused qkv GEMM, 128x128, BK=32 dbuf -------------
// 768 blocks 1D, XCD-swizzled: xcd = d&7; i = d>>3 (0..95);
// combo = xcd*8 + i/12 (0..63) -> b = combo>>4, lt = combo&15; ot = i%12.
// LDS: loop 32KB (W dbuf 16KB + X dbuf 16KB), epilogue 33.3KB -> 4 blocks/CU.
// Swizzle (mod-4): LDS slot s of row r holds global group s^(r&3).
__global__ __launch_bounds__(256) void proj_kernel(
    const u16* __restrict__ wcat, const u16* __restrict__ xT,
    const float* __restrict__ bq, const float* __restrict__ bk,
    const float* __restrict__ bv,
    u16* __restrict__ qt, u16* __restrict__ kt, u16* __restrict__ vv)
{
    const int d = blockIdx.x;
    const int i = d >> 3;                    // 0..95
    const int combo = (d & 7) * 8 + i / 12;  // 0..63  (b,lt)
    const int ot = i % 12;
    const int b  = combo >> 4;
    const int lt = combo & 15;
    const int l0 = lt * 128, o0 = ot * 128;
    const int sel = o0 >> 9, ol0 = o0 & 511;
    const float* __restrict__ bias = (sel == 0) ? bq : (sel == 1) ? bk : bv;

    __shared__ __align__(16) u16 pls[16640];     // 33.3KB (epilogue 130*128)
    u16* wtb = pls;                              // wt[BUF] = pls + BUF*4096
    u16* xtb = pls + 8192;                       // xt[BUF] = pls+8192 + BUF*4096

    const int tid = threadIdx.x, wid = tid >> 6, lane = tid & 63;
    const int hlf = lane >> 5, i32 = lane & 31;
    const int wo = wid >> 1, wl = wid & 1;
    const int srow = lane >> 2, sslot = lane & 3;   // staging row/slot in call

    f32x16 acc[2][2];
#pragma unroll
    for (int a = 0; a < 2; ++a)
#pragma unroll
        for (int c = 0; c < 2; ++c)
#pragma unroll
            for (int r = 0; r < 16; ++r) acc[a][c][r] = 0.f;

    // 4 g2l16 per wave per K-step: 2 W calls + 2 X calls (each 16 rows x 32 u16)
#define STAGE_P(C0, BUF) do {                                                     \
    _Pragma("unroll")                                                             \
    for (int cc = 0; cc < 2; ++cc) {                                              \
        int j = wid * 2 + cc;                 /* 0..7 */                          \
        int rw = j * 16 + srow;                                                   \
        int sg = ((sslot ^ (rw & 3)) << 3);                                       \
        g2l16(wcat + (size_t)(o0 + rw) * 512 + (C0) + sg,                         \
              wtb + (BUF) * 4096 + j * 512);                                      \
        g2l16(xT + ((size_t)(b * 2048 + l0 + rw)) * 512 + (C0) + sg,              \
              xtb + (BUF) * 4096 + j * 512);                                      \
    } } while (0)

    STAGE_P(0, 0);

    for (int it = 0; it < 16; ++it) {
        const int cb = it & 1;
        if (it < 15) {
            STAGE_P((it + 1) * 32, cb ^ 1);   // safe: buf^1 reads ended before
            WAITV(4);                         //   prior end-of-iter barrier
        } else {
            WAITV(0);
        }
        SBAR;
        SCHED0;
        const u16* wt = wtb + cb * 4096;
        const u16* xt = xtb + cb * 4096;
        bf16x8 wf[2][2], xf[2][2];
#pragma unroll
        for (int a = 0; a < 2; ++a)
#pragma unroll
            for (int ks = 0; ks < 2; ++ks) {
                int rw = wo * 64 + a * 32 + i32;
                wf[a][ks] = *(const bf16x8*)(wt + rw * 32 + (((ks * 2 + hlf) ^ (rw & 3)) << 3));
                int rx = wl * 64 + a * 32 + i32;
                xf[a][ks] = *(const bf16x8*)(xt + rx * 32 + (((ks * 2 + hlf) ^ (rx & 3)) << 3));
            }
        if (sel < 2) {
#pragma unroll
            for (int a = 0; a < 2; ++a)
#pragma unroll
                for (int c = 0; c < 2; ++c)
#pragma unroll
                    for (int ks = 0; ks < 2; ++ks)
                        acc[a][c] = __builtin_amdgcn_mfma_f32_32x32x16_bf16(xf[a][ks], wf[c][ks], acc[a][c], 0, 0, 0);
        } else {
#pragma unroll
            for (int a = 0; a < 2; ++a)
#pragma unroll
                for (int c = 0; c < 2; ++c)
#pragma unroll
                    for (int ks = 0; ks < 2; ++ks)
                        acc[a][c] = __builtin_amdgcn_mfma_f32_32x32x16_bf16(wf[a][ks], xf[c][ks], acc[a][c], 0, 0, 0);
        }
        WAITL0;
        SCHED0;
        SBAR;
    }
#undef STAGE_P

    // ---- r19-proven epilogue: LDS transpose (stride 130) + vector stores ----
    u16* tl = pls;

    if (sel < 2) {
        u16* __restrict__ dst = (sel == 0) ? qt : kt;
        const float sc = (sel == 0) ? SCALE_Q : 1.0f;
#pragma unroll
        for (int cslot = 0; cslot < 2; ++cslot) {
            int cg = ol0 + wo * 64 + cslot * 32 + i32;
            float bb = bias[cg];
            int ctl = wo * 64 + cslot * 32 + i32;
#pragma unroll
            for (int a = 0; a < 2; ++a)
#pragma unroll
                for (int r = 0; r < 16; ++r) {
                    int l = wl * 64 + a * 32 + (r & 3) + 8 * (r >> 2) + 4 * hlf;
                    tl[l * 130 + ctl] = f2b((acc[a][cslot][r] + bb) * sc);
                }
        }
        __syncthreads();
#pragma unroll
        for (int j = 0; j < 8; ++j) {
            int idx = j * 256 + tid;          // 0..2047
            int rh = idx >> 3;                // 0..255 = hh*128 + lp
            int c6 = (idx & 7) * 8;
            int hh = rh >> 7, lp = rh & 127;
            u16x8 v = *(const u16x8*)(tl + lp * 130 + hh * 64 + c6);
            int h = (ol0 >> 6) + hh;
            *(u16x8*)(dst + (((size_t)(b * 8 + h)) * 2048 + l0 + lp) * 64 + c6) = v;
        }
    } else {
#pragma unroll
        for (int a = 0; a < 2; ++a)
#pragma unroll
            for (int r = 0; r < 16; ++r) {
                int ovl = wo * 64 + a * 32 + (r & 3) + 8 * (r >> 2) + 4 * hlf;
                float bb = bias[ol0 + ovl];
#pragma unroll
                for (int cslot = 0; cslot < 2; ++cslot) {
                    int l = wl * 64 + cslot * 32 + i32;
                    tl[ovl * 130 + l] = f2b(acc[a][cslot][r] + bb);
                }
            }
        __syncthreads();
#pragma unroll
        for (int j = 0; j < 8; ++j) {
            int idx = j * 256 + tid;          // 0..2047
            int ovr = idx >> 4;               // 0..127
            int lc = (idx & 15) * 8;
            u16x8 v = *(const u16x8*)(tl + ovr * 130 + lc);
            *(u16x8*)(vv + ((size_t)(b * 512 + ol0 + ovr)) * 2048 + l0 + lc) = v;
        }
    }
}

// ---------------- vtrans: V (v2 rows) -> V^T (b,h,c,m) ----------------
__global__ __launch_bounds__(256) void vtrans_kernel(
    const u16* __restrict__ vv, u16* __restrict__ vtg)
{
    const int bh = blockIdx.x >> 5, mt = blockIdx.x & 31;
    const u16* __restrict__ src = vv + (size_t)bh * 131072 + mt * 4096;
    __shared__ u16 lds[64 * 65];
    const int t = threadIdx.x;
    const int m = t >> 2, c16 = (t & 3) * 16;
    u16x8 a = *(const u16x8*)(src + t * 16);
    u16x8 b = *(const u16x8*)(src + t * 16 + 8);
#pragma unroll
    for (int i = 0; i < 8; ++i) lds[(c16 + i) * 65 + m] = a[i];
#pragma unroll
    for (int i = 0; i < 8; ++i) lds[(c16 + 8 + i) * 65 + m] = b[i];
    __syncthreads();
    const int c = t >> 2, m16 = (t & 3) * 16;
    u16x8 o0, o1;
#pragma unroll
    for (int i = 0; i < 8; ++i) o0[i] = lds[c * 65 + m16 + i];
#pragma unroll
    for (int i = 0; i < 8; ++i) o1[i] = lds[c * 65 + m16 + 8 + i];
    u16* d = vtg + (size_t)bh * 131072 + (size_t)c * 2048 + mt * 64 + m16;
    *(u16x8*)d = o0;
    *(u16x8*)(d + 8) = o1;
}

// ---------------- attn: r15 flash loop, bf16 partials ----------------
// 1024 blocks (1D). work w = (d&7)*128 + d/8; lt = w&15; bh = (w>>4)>>1;
// mh = (w>>4)&1. Each XCD gets 128 consecutive w = 8 (bh,mh) K/V-halves (2MB).
__global__ __launch_bounds__(256, 4) void attn_kernel(
    const u16* __restrict__ qt, const u16* __restrict__ kt,
    const u16* __restrict__ vtg,
    u16* __restrict__ p0b, u16* __restrict__ p1b,
    float* __restrict__ ls0, float* __restrict__ ls1)
{
    const int d = blockIdx.x;
    const int w = (d & 7) * 128 + (d >> 3);
    const int lt = w & 15;
    const int g  = w >> 4;
    const int bh = g >> 1;
    const int mh = g & 1;
    const int l0 = lt * 128;
    const int tid = threadIdx.x, wid = tid >> 6, lane = tid & 63;
    const int hlf = lane >> 5, i32 = lane & 31;
    const int lrow = lane >> 3, lg = lane & 7;

    __shared__ __align__(16) u16 smem[16384];   // 32KB: K dbuf 16KB + V dbuf 16KB
    float* olds = (float*)smem;

    bf16x8 qf[4];
    {
        const u16* qrow = qt + ((size_t)bh * 2048 + l0 + wid * 32 + i32) * 64;
#pragma unroll
        for (int ks = 0; ks < 4; ++ks)
            qf[ks] = *(const bf16x8*)(qrow + ks * 16 + hlf * 8);
    }
    const u16* __restrict__ kb = kt + (size_t)bh * 2048 * 64;
    const u16* __restrict__ vb = vtg + (size_t)bh * 131072;

    float l_loc = 0.f;
    f32x16 oacc[2];
#pragma unroll
    for (int c = 0; c < 2; ++c)
#pragma unroll
        for (int r = 0; r < 16; ++r) oacc[c][r] = 0.f;

    // 16 chunks/tile split 4 ways: waves 0,1 stage K rows, waves 2,3 stage V^T rows.
#define STAGE(T, BUF) do {                                                        \
    if (wid < 2) {                                                                \
        _Pragma("unroll")                                                         \
        for (int cc = 0; cc < 4; ++cc) {                                          \
            int row = wid * 32 + cc * 8 + lrow;                                   \
            g2l16(kb + (size_t)((T) * 64 + row) * 64 + ((lg ^ lrow) << 3),        \
                  smem + (BUF) * 4096 + (wid * 4 + cc) * 512);                    \
        }                                                                         \
    } else {                                                                      \
        _Pragma("unroll")                                                         \
        for (int cc = 0; cc < 4; ++cc) {                                          \
            int crow = (wid - 2) * 32 + cc * 8 + lrow;                            \
            g2l16(vb + (size_t)crow * 2048 + (T) * 64 + ((lg ^ lrow) << 3),       \
                  smem + 8192 + (BUF) * 4096 + ((wid - 2) * 4 + cc) * 512);       \
        }                                                                         \
    } } while (0)

    const int t0 = mh * 16;
    STAGE(t0, 0);

    for (int t = 0; t < 16; ++t) {
        const int cb = t & 1;
        if (t < 15) {
            STAGE(t0 + t + 1, cb ^ 1);
            WAITV(4);              // own tile-t loads done (t+1's 4 still fly)
        } else {
            WAITV(0);
        }
        SBAR;
        SCHED0;

        const u16* kbuf = smem + cb * 4096;
        const u16* vbuf = smem + 8192 + cb * 4096;

        // St = K . Q^T  (D[m][l])
        f32x16 st[2];
        __builtin_amdgcn_s_setprio(1);
#pragma unroll
        for (int mi = 0; mi < 2; ++mi) {
#pragma unroll
            for (int r = 0; r < 16; ++r) st[mi][r] = 0.f;
#pragma unroll
            for (int ks = 0; ks < 4; ++ks) {
                int row = mi * 32 + i32;
                bf16x8 kf = *(const bf16x8*)(kbuf + row * 64 + (((ks * 2 + hlf) ^ (row & 7)) << 3));
                st[mi] = __builtin_amdgcn_mfma_f32_32x32x16_bf16(kf, qf[ks], st[mi], 0, 0, 0);
            }
        }
        __builtin_amdgcn_s_setprio(0);

        // no-max softmax + l partial (VALU)
        float psum = 0.f;
#pragma unroll
        for (int mi = 0; mi < 2; ++mi)
#pragma unroll
            for (int r = 0; r < 16; ++r) {
                st[mi][r] = exp2_(st[mi][r]);
                psum += st[mi][r];
            }
        l_loc += psum;

        // P -> B-fragments in-register (cvt_pk + permlane32_swap)
        bf16x8 pf[4];
#pragma unroll
        for (int ks = 0; ks < 4; ++ks) {
            int mi = ks >> 1, rb = (ks & 1) * 8;
            u32 A1 = cvtpk(st[mi][rb + 0], st[mi][rb + 1]);
            u32 B1 = cvtpk(st[mi][rb + 2], st[mi][rb + 3]);
            u32 A2 = cvtpk(st[mi][rb + 4], st[mi][rb + 5]);
            u32 B2 = cvtpk(st[mi][rb + 6], st[mi][rb + 7]);
            pl32swap(A1, A2);
            pl32swap(B1, B2);
            union { u32 ww[4]; bf16x8 v; } u;
            u.ww[0] = A1; u.ww[1] = B1; u.ww[2] = A2; u.ww[3] = B2;
            pf[ks] = u.v;
        }

        // O^T += V^T . P^T
        __builtin_amdgcn_s_setprio(1);
#pragma unroll
        for (int ci = 0; ci < 2; ++ci)
#pragma unroll
            for (int ks = 0; ks < 4; ++ks) {
                int row = ci * 32 + i32;
                bf16x8 vf = *(const bf16x8*)(vbuf + row * 64 + (((ks * 2 + hlf) ^ (row & 7)) << 3));
                oacc[ci] = __builtin_amdgcn_mfma_f32_32x32x16_bf16(vf, pf[ks], oacc[ci], 0, 0, 0);
            }
        __builtin_amdgcn_s_setprio(0);

        WAITL0;
        SCHED0;
        SBAR;
    }

    // l across the two row-halves (lanes l and l+32 hold complementary m-sets)
    float lfull = l_loc + __shfl_xor(l_loc, 32);
    if (lane < 32) {
        size_t ridx = (size_t)bh * 2048 + l0 + wid * 32 + lane;
        ((mh == 0) ? ls0 : ls1)[ridx] = lfull;
    }

    // epilogue: transpose raw (unnorm) O^T via fp32 LDS, pack bf16, store 8B
    u16* dstbase = ((mh == 0) ? p0b : p1b) + (size_t)bh * 131072;
    int ll = wid * 32 + i32;
    SCHED0;
#pragma unroll
    for (int ci = 0; ci < 2; ++ci)
#pragma unroll
        for (int r = 0; r < 16; ++r) {
            int c = ci * 32 + (r & 3) + 8 * (r >> 2) + 4 * hlf;
            olds[ll * 64 + (c ^ ((ll & 7) << 2))] = oacc[ci][r];
        }
    __syncthreads();
    {
        int l = tid >> 1, hv = tid & 1;
        u16* prow = dstbase + (size_t)(l0 + l) * 64;
#pragma unroll
        for (int i = 0; i < 8; ++i) {
            int c4 = hv * 8 + i;
            float4 v = *(const float4*)(olds + l * 64 + ((c4 ^ (l & 7)) << 2));
            ushort4 s;
            s.x = f2b(v.x); s.y = f2b(v.y); s.z = f2b(v.z); s.w = f2b(v.w);
            *(ushort4*)(prow + c4 * 4) = s;
        }
    }
#undef STAGE
}

// ---------------- combine: out = (b2f(p0) + b2f(p1)) / (l0 + l1) -----------
__global__ __launch_bounds__(256) void combine_kernel(
    float* __restrict__ out,
    const u16* __restrict__ p0b, const u16* __restrict__ p1b,
    const float* __restrict__ ls0, const float* __restrict__ ls1)
{
    int q = blockIdx.x * 256 + threadIdx.x;   // quad index, 1048576 total
    int e = q * 4;
    int row = e >> 6;                          // bh*2048 + l
    float inv = 1.0f / (ls0[row] + ls1[row]);
    ushort4 a = *(const ushort4*)(p0b + e);
    ushort4 b = *(const ushort4*)(p1b + e);
    float4 r;
    r.x = (b2f(a.x) + b2f(b.x)) * inv;
    r.y = (b2f(a.y) + b2f(b.y)) * inv;
    r.z = (b2f(a.z) + b2f(b.z)) * inv;
    r.w = (b2f(a.w) + b2f(b.w)) * inv;
    *(float4*)(out + e) = r;
}

extern "C" void kernel_launch(void* const* d_in, const int* in_sizes, int n_in,
                              void* d_out, int out_size, void* d_ws, size_t ws_size,
                              hipStream_t stream) {
    const float* x  = (const float*)d_in[0];
    const float* wq = (const float*)d_in[1];
    const float* bq = (const float*)d_in[2];
    const float* wk = (const float*)d_in[3];
    const float* bk = (const float*)d_in[4];
    const float* wv = (const float*)d_in[5];
    const float* bv = (const float*)d_in[6];
    float* out = (float*)d_out;

    u16* wcat = (u16*)d_ws;                 // 786432 u16 (dead after proj -> l stats)
    u16* xT   = wcat + 786432;              // 4194304 u16 (dead after proj -> p0b)
    u16* qt   = xT + 4194304;
    u16* kt   = qt + 4194304;
    u16* vv   = kt + 4194304;               // dead after vtrans -> p1b
    u16* vtg  = vv + 4194304;

    float* ls0 = (float*)wcat;              // 2 x 65536 fp32
    float* ls1 = ls0 + 65536;
    u16*   p0b = xT;                        // 4194304 u16 bf16 partial (mh=0)
    u16*   p1b = vv;                        // 4194304 u16 bf16 partial (mh=1)

    prep_kernel<<<1408, 256, 0, stream>>>(wq, wk, wv, x, wcat, xT);
    proj_kernel<<<768, 256, 0, stream>>>(wcat, xT, bq, bk, bv, qt, kt, vv);
    vtrans_kernel<<<1024, 256, 0, stream>>>(vv, vtg);
    attn_kernel<<<1024, 256, 0, stream>>>(qt, kt, vtg, p0b, p1b, ls0, ls1);
    combine_kernel<<<4096, 256, 0, stream>>>(out, p0b, p1b, ls0, ls1);
}

// Round 21
// 96.585 us; speedup vs baseline: 1.0753x; 1.0753x over previous
//
#include <hip/hip_runtime.h>

// B=4, C=512, L=2048, H=8, Ch=64, BH=32
// FINAL-KNOWN-BEST (r19 config, reverted from r20's BK=32 regression):
// prep: w->bf16 wcat[1536][512]; x->xT[b][l][c] bf16
// proj: MFMA 32x32x16, 128x128 tile, BK=64 double-buffered prefetch
//       (pre-barrier STAGE + counted WAITV(8)) + LDS-transpose vector epilogue.
// vtrans: vv -> vtg (b,h,c,m) bf16  (V^T of the .view-reshaped v2)
// attn: flash loop (LDS dbuf, two barriers, pre-barrier STAGE, no-max softmax,
//       VALU l-sum, XCD swizzle, setprio, bf16 partials).
// combine: out = (b2f(p0) + b2f(p1)) / (l0 + l1)

typedef unsigned short u16;
typedef unsigned int   u32;
typedef short bf16x8 __attribute__((ext_vector_type(8)));
typedef u16  u16x8  __attribute__((ext_vector_type(8)));
typedef float f32x16 __attribute__((ext_vector_type(16)));

#define SCALE_Q 0.18033688011112042f  // 0.125 * log2(e)

__device__ __forceinline__ u16 f2b(float f) {
    u32 u = __float_as_uint(f);
    u += 0x7FFFu + ((u >> 16) & 1u);
    return (u16)(u >> 16);
}

__device__ __forceinline__ float b2f(u16 v) {
    u32 u = ((u32)v) << 16;
    return __uint_as_float(u);
}

__device__ __forceinline__ float exp2_(float x) {
#if __has_builtin(__builtin_amdgcn_exp2f)
    return __builtin_amdgcn_exp2f(x);
#else
    return exp2f(x);
#endif
}

__device__ __forceinline__ u32 cvtpk(float lo, float hi) {
    u32 d;
    asm("v_cvt_pk_bf16_f32 %0, %1, %2" : "=v"(d) : "v"(lo), "v"(hi));
    return d;
}

__device__ __forceinline__ void pl32swap(u32& a, u32& b) {
    asm volatile("v_permlane32_swap_b32 %0, %1" : "+v"(a), "+v"(b));
}

__device__ __forceinline__ void g2l16(const u16* g, u16* l) {
    __builtin_amdgcn_global_load_lds(
        (const __attribute__((address_space(1))) unsigned int*)g,
        (__attribute__((address_space(3))) unsigned int*)l, 16, 0, 0);
}

#define WAITV(N) asm volatile("s_waitcnt vmcnt(" #N ")" ::: "memory")
#define WAITL0   asm volatile("s_waitcnt lgkmcnt(0)" ::: "memory")
#define SBAR     __builtin_amdgcn_s_barrier()
#define SCHED0   __builtin_amdgcn_sched_barrier(0)

// ---------------- prep: convert W, transpose+convert X ----------------
__global__ __launch_bounds__(256) void prep_kernel(
    const float* __restrict__ wq, const float* __restrict__ wk,
    const float* __restrict__ wv, const float* __restrict__ x,
    u16* __restrict__ wcat, u16* __restrict__ xT)
{
    const int bid = blockIdx.x, t = threadIdx.x;
    if (bid < 384) {
        int e0 = bid * 2048 + t * 8;
        const float* src = (e0 < 262144) ? wq : (e0 < 524288) ? wk : wv;
        int eo = e0 & 262143;
        float4 a = *(const float4*)(src + eo);
        float4 b = *(const float4*)(src + eo + 4);
        u16x8 o;
        o[0]=f2b(a.x); o[1]=f2b(a.y); o[2]=f2b(a.z); o[3]=f2b(a.w);
        o[4]=f2b(b.x); o[5]=f2b(b.y); o[6]=f2b(b.z); o[7]=f2b(b.w);
        *(u16x8*)(wcat + e0) = o;
        return;
    }
    int xb = bid - 384;
    int b = xb >> 8, ct = (xb >> 5) & 7, lt = xb & 31;
    __shared__ float lds[64 * 65];
#pragma unroll
    for (int it = 0; it < 4; ++it) {
        int s = t + it * 256;
        int cr = s >> 4, l4 = (s & 15) * 4;
        float4 v = *(const float4*)(x + ((size_t)(b * 512 + ct * 64 + cr)) * 2048 + lt * 64 + l4);
        lds[(l4 + 0) * 65 + cr] = v.x;
        lds[(l4 + 1) * 65 + cr] = v.y;
        lds[(l4 + 2) * 65 + cr] = v.z;
        lds[(l4 + 3) * 65 + cr] = v.w;
    }
    __syncthreads();
    {
        int l = t >> 2, c16 = (t & 3) * 16;
        u16x8 o0, o1;
#pragma unroll
        for (int i = 0; i < 8; ++i) o0[i] = f2b(lds[l * 65 + c16 + i]);
#pragma unroll
        for (int i = 0; i < 8; ++i) o1[i] = f2b(lds[l * 65 + c16 + 8 + i]);
        u16* d = xT + ((size_t)(b * 2048 + lt * 64 + l)) * 512 + ct * 64 + c16;
        *(u16x8*)d = o0;
        *(u16x8*)(d + 8) = o1;
    }
}

// ---------------- proj: fused qkv GEMM, 128x128, dbuf + vector epilogue ----
// 768 blocks 1D, XCD-swizzled: xcd = d&7; i = d>>3 (0..95);
// combo = xcd*8 + i/12 (0..63) -> b = combo>>4, lt = combo&15; ot = i%12.
__global__ __launch_bounds__(256) void proj_kernel(
    const u16* __restrict__ wcat, const u16* __restrict__ xT,
    const float* __restrict__ bq, const float* __restrict__ bk,
    const float* __restrict__ bv,
    u16* __restrict__ qt, u16* __restrict__ kt, u16* __restrict__ vv)
{
    const int d = blockIdx.x;
    const int i = d >> 3;                    // 0..95
    const int combo = (d & 7) * 8 + i / 12;  // 0..63  (b,lt)
    const int ot = i % 12;
    const int b  = combo >> 4;
    const int lt = combo & 15;
    const int l0 = lt * 128, o0 = ot * 128;
    const int sel = o0 >> 9, ol0 = o0 & 511;
    const float* __restrict__ bias = (sel == 0) ? bq : (sel == 1) ? bk : bv;

    __shared__ __align__(16) u16 pls[32768];     // 64KB: wt dbuf 32KB + xt dbuf 32KB
    u16* wtb = pls;                              // wt[BUF] = pls + BUF*8192
    u16* xtb = pls + 16384;                      // xt[BUF] = pls+16384 + BUF*8192

    const int tid = threadIdx.x, wid = tid >> 6, lane = tid & 63;
    const int hlf = lane >> 5, i32 = lane & 31;
    const int lrow = lane >> 3, lg = lane & 7;
    const int wo = wid >> 1, wl = wid & 1;

    f32x16 acc[2][2];
#pragma unroll
    for (int a = 0; a < 2; ++a)
#pragma unroll
        for (int c = 0; c < 2; ++c)
#pragma unroll
            for (int r = 0; r < 16; ++r) acc[a][c][r] = 0.f;

    // 8 g2l16 per wave per K-step (4 W chunks + 4 X chunks)
#define STAGE_P(C0, BUF) do {                                                     \
    _Pragma("unroll")                                                             \
    for (int cc = 0; cc < 4; ++cc) {                                              \
        int rb = (wid * 4 + cc) * 8;                                              \
        int rw = rb + lrow;                                                       \
        int sg = (lg ^ (rw & 7)) << 3;                                            \
        g2l16(wcat + (size_t)(o0 + rw) * 512 + (C0) + sg,                         \
              wtb + (BUF) * 8192 + rb * 64);                                      \
        g2l16(xT + ((size_t)(b * 2048 + l0 + rw)) * 512 + (C0) + sg,              \
              xtb + (BUF) * 8192 + rb * 64);                                      \
    } } while (0)

    STAGE_P(0, 0);

    for (int it = 0; it < 8; ++it) {
        const int cb = it & 1;
        if (it < 7) {
            STAGE_P((it + 1) * 64, cb ^ 1);   // safe: buf^1 reads ended before
            WAITV(8);                         //   prior end-of-iter barrier
        } else {
            WAITV(0);
        }
        SBAR;
        SCHED0;
        const u16* wt = wtb + cb * 8192;
        const u16* xt = xtb + cb * 8192;
        bf16x8 wf[2][4], xf[2][4];
#pragma unroll
        for (int a = 0; a < 2; ++a)
#pragma unroll
            for (int ks = 0; ks < 4; ++ks) {
                int rw = wo * 64 + a * 32 + i32;
                wf[a][ks] = *(const bf16x8*)(wt + rw * 64 + (((ks * 2 + hlf) ^ (rw & 7)) << 3));
                int rx = wl * 64 + a * 32 + i32;
                xf[a][ks] = *(const bf16x8*)(xt + rx * 64 + (((ks * 2 + hlf) ^ (rx & 7)) << 3));
            }
        if (sel < 2) {
#pragma unroll
            for (int a = 0; a < 2; ++a)
#pragma unroll
                for (int c = 0; c < 2; ++c)
#pragma unroll
                    for (int ks = 0; ks < 4; ++ks)
                        acc[a][c] = __builtin_amdgcn_mfma_f32_32x32x16_bf16(xf[a][ks], wf[c][ks], acc[a][c], 0, 0, 0);
        } else {
#pragma unroll
            for (int a = 0; a < 2; ++a)
#pragma unroll
                for (int c = 0; c < 2; ++c)
#pragma unroll
                    for (int ks = 0; ks < 4; ++ks)
                        acc[a][c] = __builtin_amdgcn_mfma_f32_32x32x16_bf16(wf[a][ks], xf[c][ks], acc[a][c], 0, 0, 0);
        }
        WAITL0;
        SCHED0;
        SBAR;
    }
#undef STAGE_P

    // ---- epilogue: LDS transpose (stride 130, conflict-spread) then
    //      full-line vector stores. tl = pls (33.3KB of the 64KB). ----
    u16* tl = pls;

    if (sel < 2) {
        u16* __restrict__ dst = (sel == 0) ? qt : kt;
        const float sc = (sel == 0) ? SCALE_Q : 1.0f;
        // write: tl[l][c]  (l 0..127 tile-local, c 0..127 tile-local)
#pragma unroll
        for (int cslot = 0; cslot < 2; ++cslot) {
            int cg = ol0 + wo * 64 + cslot * 32 + i32;
            float bb = bias[cg];
            int ctl = wo * 64 + cslot * 32 + i32;
#pragma unroll
            for (int a = 0; a < 2; ++a)
#pragma unroll
                for (int r = 0; r < 16; ++r) {
                    int l = wl * 64 + a * 32 + (r & 3) + 8 * (r >> 2) + 4 * hlf;
                    tl[l * 130 + ctl] = f2b((acc[a][cslot][r] + bb) * sc);
                }
        }
        __syncthreads();
        // store: 2048 chunks of u16x8; 8 lanes = one 128B head-row line
#pragma unroll
        for (int j = 0; j < 8; ++j) {
            int idx = j * 256 + tid;          // 0..2047
            int rh = idx >> 3;                // 0..255 = hh*128 + lp
            int c6 = (idx & 7) * 8;
            int hh = rh >> 7, lp = rh & 127;
            u16x8 v = *(const u16x8*)(tl + lp * 130 + hh * 64 + c6);
            int h = (ol0 >> 6) + hh;
            *(u16x8*)(dst + (((size_t)(b * 8 + h)) * 2048 + l0 + lp) * 64 + c6) = v;
        }
    } else {
        // write: tl[ov][l]  (ov 0..127 tile-local, l 0..127 tile-local)
#pragma unroll
        for (int a = 0; a < 2; ++a)
#pragma unroll
            for (int r = 0; r < 16; ++r) {
                int ovl = wo * 64 + a * 32 + (r & 3) + 8 * (r >> 2) + 4 * hlf;
                float bb = bias[ol0 + ovl];
#pragma unroll
                for (int cslot = 0; cslot < 2; ++cslot) {
                    int l = wl * 64 + cslot * 32 + i32;
                    tl[ovl * 130 + l] = f2b(acc[a][cslot][r] + bb);
                }
            }
        __syncthreads();
        // store: 2048 chunks of u16x8; 16 lanes = one 256B channel-row chunk
#pragma unroll
        for (int j = 0; j < 8; ++j) {
            int idx = j * 256 + tid;          // 0..2047
            int ovr = idx >> 4;               // 0..127
            int lc = (idx & 15) * 8;
            u16x8 v = *(const u16x8*)(tl + ovr * 130 + lc);
            *(u16x8*)(vv + ((size_t)(b * 512 + ol0 + ovr)) * 2048 + l0 + lc) = v;
        }
    }
}

// ---------------- vtrans: V (v2 rows) -> V^T (b,h,c,m) ----------------
__global__ __launch_bounds__(256) void vtrans_kernel(
    const u16* __restrict__ vv, u16* __restrict__ vtg)
{
    const int bh = blockIdx.x >> 5, mt = blockIdx.x & 31;
    const u16* __restrict__ src = vv + (size_t)bh * 131072 + mt * 4096;
    __shared__ u16 lds[64 * 65];
    const int t = threadIdx.x;
    const int m = t >> 2, c16 = (t & 3) * 16;
    u16x8 a = *(const u16x8*)(src + t * 16);
    u16x8 b = *(const u16x8*)(src + t * 16 + 8);
#pragma unroll
    for (int i = 0; i < 8; ++i) lds[(c16 + i) * 65 + m] = a[i];
#pragma unroll
    for (int i = 0; i < 8; ++i) lds[(c16 + 8 + i) * 65 + m] = b[i];
    __syncthreads();
    const int c = t >> 2, m16 = (t & 3) * 16;
    u16x8 o0, o1;
#pragma unroll
    for (int i = 0; i < 8; ++i) o0[i] = lds[c * 65 + m16 + i];
#pragma unroll
    for (int i = 0; i < 8; ++i) o1[i] = lds[c * 65 + m16 + 8 + i];
    u16* d = vtg + (size_t)bh * 131072 + (size_t)c * 2048 + mt * 64 + m16;
    *(u16x8*)d = o0;
    *(u16x8*)(d + 8) = o1;
}

// ---------------- attn: flash loop, bf16 partials ----------------
// 1024 blocks (1D). work w = (d&7)*128 + d/8; lt = w&15; bh = (w>>4)>>1;
// mh = (w>>4)&1. Each XCD gets 128 consecutive w = 8 (bh,mh) K/V-halves (2MB).
__global__ __launch_bounds__(256, 4) void attn_kernel(
    const u16* __restrict__ qt, const u16* __restrict__ kt,
    const u16* __restrict__ vtg,
    u16* __restrict__ p0b, u16* __restrict__ p1b,
    float* __restrict__ ls0, float* __restrict__ ls1)
{
    const int d = blockIdx.x;
    const int w = (d & 7) * 128 + (d >> 3);
    const int lt = w & 15;
    const int g  = w >> 4;
    const int bh = g >> 1;
    const int mh = g & 1;
    const int l0 = lt * 128;
    const int tid = threadIdx.x, wid = tid >> 6, lane = tid & 63;
    const int hlf = lane >> 5, i32 = lane & 31;
    const int lrow = lane >> 3, lg = lane & 7;

    __shared__ __align__(16) u16 smem[16384];   // 32KB: K dbuf 16KB + V dbuf 16KB
    float* olds = (float*)smem;

    bf16x8 qf[4];
    {
        const u16* qrow = qt + ((size_t)bh * 2048 + l0 + wid * 32 + i32) * 64;
#pragma unroll
        for (int ks = 0; ks < 4; ++ks)
            qf[ks] = *(const bf16x8*)(qrow + ks * 16 + hlf * 8);
    }
    const u16* __restrict__ kb = kt + (size_t)bh * 2048 * 64;
    const u16* __restrict__ vb = vtg + (size_t)bh * 131072;

    float l_loc = 0.f;
    f32x16 oacc[2];
#pragma unroll
    for (int c = 0; c < 2; ++c)
#pragma unroll
        for (int r = 0; r < 16; ++r) oacc[c][r] = 0.f;

    // 16 chunks/tile split 4 ways: waves 0,1 stage K rows, waves 2,3 stage V^T rows.
#define STAGE(T, BUF) do {                                                        \
    if (wid < 2) {                                                                \
        _Pragma("unroll")                                                         \
        for (int cc = 0; cc < 4; ++cc) {                                          \
            int row = wid * 32 + cc * 8 + lrow;                                   \
            g2l16(kb + (size_t)((T) * 64 + row) * 64 + ((lg ^ lrow) << 3),        \
                  smem + (BUF) * 4096 + (wid * 4 + cc) * 512);                    \
        }                                                                         \
    } else {                                                                      \
        _Pragma("unroll")                                                         \
        for (int cc = 0; cc < 4; ++cc) {                                          \
            int crow = (wid - 2) * 32 + cc * 8 + lrow;                            \
            g2l16(vb + (size_t)crow * 2048 + (T) * 64 + ((lg ^ lrow) << 3),       \
                  smem + 8192 + (BUF) * 4096 + ((wid - 2) * 4 + cc) * 512);       \
        }                                                                         \
    } } while (0)

    const int t0 = mh * 16;
    STAGE(t0, 0);

    for (int t = 0; t < 16; ++t) {
        const int cb = t & 1;
        if (t < 15) {
            STAGE(t0 + t + 1, cb ^ 1);
            WAITV(4);              // own tile-t loads done (t+1's 4 still fly)
        } else {
            WAITV(0);
        }
        SBAR;
        SCHED0;

        const u16* kbuf = smem + cb * 4096;
        const u16* vbuf = smem + 8192 + cb * 4096;

        // St = K . Q^T  (D[m][l])
        f32x16 st[2];
        __builtin_amdgcn_s_setprio(1);
#pragma unroll
        for (int mi = 0; mi < 2; ++mi) {
#pragma unroll
            for (int r = 0; r < 16; ++r) st[mi][r] = 0.f;
#pragma unroll
            for (int ks = 0; ks < 4; ++ks) {
                int row = mi * 32 + i32;
                bf16x8 kf = *(const bf16x8*)(kbuf + row * 64 + (((ks * 2 + hlf) ^ (row & 7)) << 3));
                st[mi] = __builtin_amdgcn_mfma_f32_32x32x16_bf16(kf, qf[ks], st[mi], 0, 0, 0);
            }
        }
        __builtin_amdgcn_s_setprio(0);

        // no-max softmax + l partial (VALU)
        float psum = 0.f;
#pragma unroll
        for (int mi = 0; mi < 2; ++mi)
#pragma unroll
            for (int r = 0; r < 16; ++r) {
                st[mi][r] = exp2_(st[mi][r]);
                psum += st[mi][r];
            }
        l_loc += psum;

        // P -> B-fragments in-register (cvt_pk + permlane32_swap)
        bf16x8 pf[4];
#pragma unroll
        for (int ks = 0; ks < 4; ++ks) {
            int mi = ks >> 1, rb = (ks & 1) * 8;
            u32 A1 = cvtpk(st[mi][rb + 0], st[mi][rb + 1]);
            u32 B1 = cvtpk(st[mi][rb + 2], st[mi][rb + 3]);
            u32 A2 = cvtpk(st[mi][rb + 4], st[mi][rb + 5]);
            u32 B2 = cvtpk(st[mi][rb + 6], st[mi][rb + 7]);
            pl32swap(A1, A2);
            pl32swap(B1, B2);
            union { u32 ww[4]; bf16x8 v; } u;
            u.ww[0] = A1; u.ww[1] = B1; u.ww[2] = A2; u.ww[3] = B2;
            pf[ks] = u.v;
        }

        // O^T += V^T . P^T
        __builtin_amdgcn_s_setprio(1);
#pragma unroll
        for (int ci = 0; ci < 2; ++ci)
#pragma unroll
            for (int ks = 0; ks < 4; ++ks) {
                int row = ci * 32 + i32;
                bf16x8 vf = *(const bf16x8*)(vbuf + row * 64 + (((ks * 2 + hlf) ^ (row & 7)) << 3));
                oacc[ci] = __builtin_amdgcn_mfma_f32_32x32x16_bf16(vf, pf[ks], oacc[ci], 0, 0, 0);
            }
        __builtin_amdgcn_s_setprio(0);

        WAITL0;
        SCHED0;
        SBAR;
    }

    // l across the two row-halves (lanes l and l+32 hold complementary m-sets)
    float lfull = l_loc + __shfl_xor(l_loc, 32);
    if (lane < 32) {
        size_t ridx = (size_t)bh * 2048 + l0 + wid * 32 + lane;
        ((mh == 0) ? ls0 : ls1)[ridx] = lfull;
    }

    // epilogue: transpose raw (unnorm) O^T via fp32 LDS, pack bf16, store 8B
    u16* dstbase = ((mh == 0) ? p0b : p1b) + (size_t)bh * 131072;
    int ll = wid * 32 + i32;
    SCHED0;
#pragma unroll
    for (int ci = 0; ci < 2; ++ci)
#pragma unroll
        for (int r = 0; r < 16; ++r) {
            int c = ci * 32 + (r & 3) + 8 * (r >> 2) + 4 * hlf;
            olds[ll * 64 + (c ^ ((ll & 7) << 2))] = oacc[ci][r];
        }
    __syncthreads();
    {
        int l = tid >> 1, hv = tid & 1;
        u16* prow = dstbase + (size_t)(l0 + l) * 64;
#pragma unroll
        for (int i = 0; i < 8; ++i) {
            int c4 = hv * 8 + i;
            float4 v = *(const float4*)(olds + l * 64 + ((c4 ^ (l & 7)) << 2));
            ushort4 s;
            s.x = f2b(v.x); s.y = f2b(v.y); s.z = f2b(v.z); s.w = f2b(v.w);
            *(ushort4*)(prow + c4 * 4) = s;
        }
    }
#undef STAGE
}

// ---------------- combine: out = (b2f(p0) + b2f(p1)) / (l0 + l1) -----------
__global__ __launch_bounds__(256) void combine_kernel(
    float* __restrict__ out,
    const u16* __restrict__ p0b, const u16* __restrict__ p1b,
    const float* __restrict__ ls0, const float* __restrict__ ls1)
{
    int q = blockIdx.x * 256 + threadIdx.x;   // quad index, 1048576 total
    int e = q * 4;
    int row = e >> 6;                          // bh*2048 + l
    float inv = 1.0f / (ls0[row] + ls1[row]);
    ushort4 a = *(const ushort4*)(p0b + e);
    ushort4 b = *(const ushort4*)(p1b + e);
    float4 r;
    r.x = (b2f(a.x) + b2f(b.x)) * inv;
    r.y = (b2f(a.y) + b2f(b.y)) * inv;
    r.z = (b2f(a.z) + b2f(b.z)) * inv;
    r.w = (b2f(a.w) + b2f(b.w)) * inv;
    *(float4*)(out + e) = r;
}

extern "C" void kernel_launch(void* const* d_in, const int* in_sizes, int n_in,
                              void* d_out, int out_size, void* d_ws, size_t ws_size,
                              hipStream_t stream) {
    const float* x  = (const float*)d_in[0];
    const float* wq = (const float*)d_in[1];
    const float* bq = (const float*)d_in[2];
    const float* wk = (const float*)d_in[3];
    const float* bk = (const float*)d_in[4];
    const float* wv = (const float*)d_in[5];
    const float* bv = (const float*)d_in[6];
    float* out = (float*)d_out;

    u16* wcat = (u16*)d_ws;                 // 786432 u16 (dead after proj -> l stats)
    u16* xT   = wcat + 786432;              // 4194304 u16 (dead after proj -> p0b)
    u16* qt   = xT + 4194304;
    u16* kt   = qt + 4194304;
    u16* vv   = kt + 4194304;               // dead after vtrans -> p1b
    u16* vtg  = vv + 4194304;

    float* ls0 = (float*)wcat;              // 2 x 65536 fp32
    float* ls1 = ls0 + 65536;
    u16*   p0b = xT;                        // 4194304 u16 bf16 partial (mh=0)
    u16*   p1b = vv;                        // 4194304 u16 bf16 partial (mh=1)

    prep_kernel<<<1408, 256, 0, stream>>>(wq, wk, wv, x, wcat, xT);
    proj_kernel<<<768, 256, 0, stream>>>(wcat, xT, bq, bk, bv, qt, kt, vv);
    vtrans_kernel<<<1024, 256, 0, stream>>>(vv, vtg);
    attn_kernel<<<1024, 256, 0, stream>>>(qt, kt, vtg, p0b, p1b, ls0, ls1);
    combine_kernel<<<4096, 256, 0, stream>>>(out, p0b, p1b, ls0, ls1);
}